// Round 1
// baseline (4077.169 us; speedup 1.0000x reference)
//
#include <hip/hip_runtime.h>
#include <cstdint>

#define NTOK 8192
#define DM   512
#define DI   2048
#define NEXP 24
#define TPG  2048
#define CAP  171
#define CAPR 176
#define EPSF 1e-6f

// ---------------- generic 64x64 tiled GEMM: mode 0: C = A@B ; mode 1: C = relu(A@B) + Add
__global__ __launch_bounds__(256) void gemm64(
    const float* __restrict__ A, const float* __restrict__ B, float* __restrict__ C,
    const float* __restrict__ Add, int M, int N, int K, int mode)
{
  __shared__ float As[16][64];
  __shared__ float Bs[16][64];
  int tid = threadIdx.x;
  int m0 = blockIdx.y * 64, n0 = blockIdx.x * 64;
  int tm = tid & 15, tn = tid >> 4;
  int arow = tid >> 2, ac4 = tid & 3;
  int bkk = tid >> 4, bc4 = tid & 15;
  const float* aptr = A + (size_t)(m0 + arow) * K + ac4 * 4;
  const float* bptr = B + (size_t)bkk * N + n0 + bc4 * 4;
  float acc[4][4] = {};
  for (int k0 = 0; k0 < K; k0 += 16) {
    float4 av = *(const float4*)(aptr + k0);
    float4 bv = *(const float4*)(bptr + (size_t)k0 * N);
    __syncthreads();
    As[ac4*4+0][arow] = av.x;
    As[ac4*4+1][arow] = av.y;
    As[ac4*4+2][arow] = av.z;
    As[ac4*4+3][arow] = av.w;
    *(float4*)&Bs[bkk][bc4*4] = bv;
    __syncthreads();
    #pragma unroll
    for (int kk = 0; kk < 16; ++kk) {
      float4 a = *(const float4*)&As[kk][tm*4];
      float4 b = *(const float4*)&Bs[kk][tn*4];
      acc[0][0] += a.x*b.x; acc[0][1] += a.x*b.y; acc[0][2] += a.x*b.z; acc[0][3] += a.x*b.w;
      acc[1][0] += a.y*b.x; acc[1][1] += a.y*b.y; acc[1][2] += a.y*b.z; acc[1][3] += a.y*b.w;
      acc[2][0] += a.z*b.x; acc[2][1] += a.z*b.y; acc[2][2] += a.z*b.z; acc[2][3] += a.z*b.w;
      acc[3][0] += a.w*b.x; acc[3][1] += a.w*b.y; acc[3][2] += a.w*b.z; acc[3][3] += a.w*b.w;
    }
  }
  #pragma unroll
  for (int i = 0; i < 4; ++i) {
    int m = m0 + tm*4 + i;
    float* cp = C + (size_t)m * N + n0 + tn*4;
    const float* ap2 = Add ? (Add + (size_t)m * N + n0 + tn*4) : nullptr;
    #pragma unroll
    for (int j = 0; j < 4; ++j) {
      float c = acc[i][j];
      if (mode == 1) c = fmaxf(c, 0.0f) + ap2[j];
      cp[j] = c;
    }
  }
}

// ---------------- attention: one block = 8 query rows of one (b,h); scores in LDS
__global__ __launch_bounds__(256) void attn_kernel(
    const float* __restrict__ q, const float* __restrict__ k, const float* __restrict__ v,
    float* __restrict__ ctx)
{
  int tile = blockIdx.x & 127;
  int bh = blockIdx.x >> 7;
  int b = bh >> 3, h = bh & 7;
  __shared__ float sc[8][1024];
  __shared__ float ql[8][64];
  int tid = threadIdx.x;
  int n0 = tile * 8;
  size_t basebh = (size_t)b * 1024 * 512 + (size_t)h * 64;
  for (int i = tid; i < 512; i += 256) {
    int r = i >> 6, d = i & 63;
    ql[r][d] = q[basebh + (size_t)(n0 + r) * 512 + d] * 0.125f;  // q / sqrt(64)
  }
  __syncthreads();
  for (int idx = tid; idx < 8192; idx += 256) {
    int r = idx >> 10, m = idx & 1023;
    const float4* kp = (const float4*)(k + basebh + (size_t)m * 512);
    const float4* qp = (const float4*)ql[r];
    float s = 0.f;
    #pragma unroll
    for (int d4 = 0; d4 < 16; ++d4) {
      float4 kv4 = kp[d4]; float4 q4 = qp[d4];
      s += q4.x*kv4.x + q4.y*kv4.y + q4.z*kv4.z + q4.w*kv4.w;
    }
    sc[r][m] = s;
  }
  __syncthreads();
  int r = tid >> 5, lane = tid & 31;
  float mx = -1e30f;
  for (int m = lane; m < 1024; m += 32) mx = fmaxf(mx, sc[r][m]);
  #pragma unroll
  for (int o = 16; o; o >>= 1) mx = fmaxf(mx, __shfl_xor(mx, o, 64));
  float sum = 0.f;
  for (int m = lane; m < 1024; m += 32) { float e = __expf(sc[r][m] - mx); sc[r][m] = e; sum += e; }
  #pragma unroll
  for (int o = 16; o; o >>= 1) sum += __shfl_xor(sum, o, 64);
  float inv = 1.0f / sum;
  __syncthreads();
  float a0 = 0.f, a1 = 0.f;
  for (int m = 0; m < 1024; ++m) {
    float p = sc[r][m] * inv;
    const float* vp = v + basebh + (size_t)m * 512;
    a0 += p * vp[lane];
    a1 += p * vp[lane + 32];
  }
  float* cp = ctx + ((size_t)b * 1024 + n0 + r) * 512 + (size_t)h * 64;
  cp[lane] = a0; cp[lane + 32] = a1;
}

// ---------------- layernorm (optional pre-add and post-relu; per-group gamma/beta select)
__global__ __launch_bounds__(256) void ln_kernel(
    const float* __restrict__ in, const float* __restrict__ add, float* __restrict__ out,
    int D, int relu_after,
    const float* __restrict__ g0, const float* __restrict__ g1,
    const float* __restrict__ g2, const float* __restrict__ g3,
    const float* __restrict__ bb0, const float* __restrict__ bb1,
    const float* __restrict__ bb2, const float* __restrict__ bb3)
{
  int row = blockIdx.x;
  int grp = (row & 1023) >> 8;
  const float* g  = grp == 0 ? g0  : grp == 1 ? g1  : grp == 2 ? g2  : g3;
  const float* bb = grp == 0 ? bb0 : grp == 1 ? bb1 : grp == 2 ? bb2 : bb3;
  const float* ip = in + (size_t)row * D;
  const float* ap = add ? add + (size_t)row * D : nullptr;
  float vals[8];
  int per = D >> 8;
  float s1 = 0.f, s2 = 0.f;
  for (int i = 0; i < per; ++i) {
    int d = threadIdx.x + (i << 8);
    float vv = ip[d];
    if (ap) vv += ap[d];
    vals[i] = vv; s1 += vv; s2 += vv * vv;
  }
  #pragma unroll
  for (int o = 32; o; o >>= 1) { s1 += __shfl_xor(s1, o, 64); s2 += __shfl_xor(s2, o, 64); }
  __shared__ float sA[4], sB[4];
  int wid = threadIdx.x >> 6, lane = threadIdx.x & 63;
  if (lane == 0) { sA[wid] = s1; sB[wid] = s2; }
  __syncthreads();
  float t1 = sA[0] + sA[1] + sA[2] + sA[3];
  float t2 = sB[0] + sB[1] + sB[2] + sB[3];
  float mean = t1 / (float)D;
  float var = t2 / (float)D - mean * mean;
  float rs = rsqrtf(var + EPSF);
  float* op = out + (size_t)row * D;
  for (int i = 0; i < per; ++i) {
    int d = threadIdx.x + (i << 8);
    float o = (vals[i] - mean) * rs * g[d] + bb[d];
    if (relu_after) o = fmaxf(o, 0.f);
    op[d] = o;
  }
}

// ---------------- gating stage 1: per-token logits + top2 (normalized weights)
__global__ __launch_bounds__(256) void gate1(
    const float* __restrict__ xln, const float* __restrict__ wg,
    int* __restrict__ idx0, int* __restrict__ idx1,
    float* __restrict__ w0o, float* __restrict__ w1o)
{
  int wid = threadIdx.x >> 6, lane = threadIdx.x & 63;
  int tk = blockIdx.x * 4 + wid;            // 0..8191
  int g = tk >> 11, t = tk & 2047;
  int b = t >> 8, j = t & 255;
  size_t row = (size_t)b * 1024 + g * 256 + j;
  const float* xp = xln + row * 512;
  float acc = -1e30f;
  if (lane < 24) {
    acc = 0.f;
    for (int d = 0; d < 512; ++d) acc += xp[d] * wg[d * 24 + lane];
  }
  float b0v = -1e30f, b1v = -1e30f; int i0 = 0, i1 = 0;
  for (int e = 0; e < 24; ++e) {
    float vv = __shfl(acc, e, 64);
    if (vv > b0v)      { b1v = b0v; i1 = i0; b0v = vv; i0 = e; }
    else if (vv > b1v) { b1v = vv; i1 = e; }
  }
  if (lane == 0) {
    float w0 = 1.0f / (1.0f + __expf(b1v - b0v));  // softmax denom cancels in w/sum(w)
    idx0[tk] = i0; idx1[tk] = i1; w0o[tk] = w0; w1o[tk] = 1.0f - w0;
  }
}

// ---------------- gating stage 2: capacity-limited ranking -> per-(g,e) token lists
__global__ __launch_bounds__(64) void gate2(
    const int* __restrict__ idx0, const int* __restrict__ idx1,
    const float* __restrict__ w0, const float* __restrict__ w1,
    int* __restrict__ lrow, float* __restrict__ lw, int* __restrict__ counts)
{
  int pair = blockIdx.x; int g = pair / 24; int e = pair % 24;
  int lane = threadIdx.x;
  int base = g * TPG;
  unsigned long long lm = (lane == 63) ? 0x7fffffffffffffffULL : ((1ULL << lane) - 1ULL);
  int run = 0;
  for (int it = 0; it < TPG / 64; ++it) {
    int t = it * 64 + lane;
    bool m = (idx0[base + t] == e);
    unsigned long long mask = __ballot(m);
    int pre = __popcll(mask & lm);
    int rank = run + pre;
    if (m && rank < CAP) {
      int bq = t >> 8, j = t & 255;
      lrow[pair * CAPR + rank] = bq * 1024 + g * 256 + j;
      lw[pair * CAPR + rank] = w0[base + t];
    }
    run += __popcll(mask);
  }
  int total1 = run;
  int run2 = 0;
  for (int it = 0; it < TPG / 64; ++it) {
    int t = it * 64 + lane;
    bool m = (idx1[base + t] == e);
    unsigned long long mask = __ballot(m);
    int pre = __popcll(mask & lm);
    int rank2 = run2 + pre;
    if (m && (total1 + rank2) < CAP) {
      int bq = t >> 8, j = t & 255;
      lrow[pair * CAPR + total1 + rank2] = bq * 1024 + g * 256 + j;
      lw[pair * CAPR + total1 + rank2] = w1[base + t];
    }
    run2 += __popcll(mask);
  }
  if (lane == 0) {
    int c1 = total1 < CAP ? total1 : CAP;
    int room = CAP - total1; if (room < 0) room = 0;
    int c2 = run2 < room ? run2 : room;
    counts[pair] = c1 + c2;
  }
}

// ---------------- MoE expert GEMM over gathered token list; atomic weighted combine
__global__ __launch_bounds__(256) void moe_gemm(
    const float* __restrict__ X, const float* __restrict__ W, const float* __restrict__ bias,
    const int* __restrict__ lrow, const float* __restrict__ lw, const int* __restrict__ counts,
    float* __restrict__ Out, int K, int N)
{
  int pair = blockIdx.z;
  int e = pair % 24;
  int count = counts[pair];
  int m0 = blockIdx.y * 64;
  if (m0 >= count) return;
  int n0 = blockIdx.x * 64;
  __shared__ float As[16][64];
  __shared__ float Bs[16][64];
  int tid = threadIdx.x;
  int tm = tid & 15, tn = tid >> 4;
  int arow = tid >> 2, ac4 = tid & 3;
  int am = m0 + arow;
  int srow = lrow[pair * CAPR + (am < count ? am : 0)];
  const float* aptr = X + (size_t)srow * K + ac4 * 4;
  int bkk = tid >> 4, bc4 = tid & 15;
  const float* bptr = W + ((size_t)e * K + bkk) * N + n0 + bc4 * 4;
  float acc[4][4] = {};
  for (int k0 = 0; k0 < K; k0 += 16) {
    float4 av = *(const float4*)(aptr + k0);
    float4 bv = *(const float4*)(bptr + (size_t)k0 * N);
    __syncthreads();
    As[ac4*4+0][arow] = av.x;
    As[ac4*4+1][arow] = av.y;
    As[ac4*4+2][arow] = av.z;
    As[ac4*4+3][arow] = av.w;
    *(float4*)&Bs[bkk][bc4*4] = bv;
    __syncthreads();
    #pragma unroll
    for (int kk = 0; kk < 16; ++kk) {
      float4 a = *(const float4*)&As[kk][tm*4];
      float4 b = *(const float4*)&Bs[kk][tn*4];
      acc[0][0] += a.x*b.x; acc[0][1] += a.x*b.y; acc[0][2] += a.x*b.z; acc[0][3] += a.x*b.w;
      acc[1][0] += a.y*b.x; acc[1][1] += a.y*b.y; acc[1][2] += a.y*b.z; acc[1][3] += a.y*b.w;
      acc[2][0] += a.z*b.x; acc[2][1] += a.z*b.y; acc[2][2] += a.z*b.z; acc[2][3] += a.z*b.w;
      acc[3][0] += a.w*b.x; acc[3][1] += a.w*b.y; acc[3][2] += a.w*b.z; acc[3][3] += a.w*b.w;
    }
  }
  float4 biv = *(const float4*)(bias + (size_t)e * N + n0 + tn * 4);
  #pragma unroll
  for (int i = 0; i < 4; ++i) {
    int m = m0 + tm * 4 + i;
    if (m < count) {
      int r = lrow[pair * CAPR + m];
      float w = lw[pair * CAPR + m];
      float* op = Out + (size_t)r * N + n0 + tn * 4;
      atomicAdd(&op[0], w * (acc[i][0] + biv.x));
      atomicAdd(&op[1], w * (acc[i][1] + biv.y));
      atomicAdd(&op[2], w * (acc[i][2] + biv.z));
      atomicAdd(&op[3], w * (acc[i][3] + biv.w));
    }
  }
}

extern "C" void kernel_launch(void* const* d_in, const int* in_sizes, int n_in,
                              void* d_out, int out_size, void* d_ws, size_t ws_size,
                              hipStream_t stream)
{
  const float* x   = (const float*)d_in[0];
  const float* wq  = (const float*)d_in[1];
  const float* wk  = (const float*)d_in[2];
  const float* wv  = (const float*)d_in[3];
  const float* wo  = (const float*)d_in[4];
  const float* ln_attn_g = (const float*)d_in[5];
  const float* ln_attn_b = (const float*)d_in[6];
  const float* wg1 = (const float*)d_in[7];
  const float* w1  = (const float*)d_in[8];
  const float* b1  = (const float*)d_in[9];
  /* d_in[10] = wg2 — unused by reference (routing reused for both MoE layers) */
  const float* w2  = (const float*)d_in[11];
  const float* b2  = (const float*)d_in[12];
  const float* ln_out_g = (const float*)d_in[13];
  const float* ln_out_b = (const float*)d_in[14];
  const float* ln1g = (const float*)d_in[15]; const float* ln1b = (const float*)d_in[16];
  const float* ln2g = (const float*)d_in[17]; const float* ln2b = (const float*)d_in[18];
  const float* ln3g = (const float*)d_in[19]; const float* ln3b = (const float*)d_in[20];
  const float* ln4g = (const float*)d_in[21]; const float* ln4b = (const float*)d_in[22];

  char* ws = (char*)d_ws;
  float* qb    = (float*)(ws + 0);                      // q, then y0, then h (overlap)
  float* kb    = (float*)(ws + (size_t)16777216);
  float* vb    = (float*)(ws + (size_t)33554432);
  float* ctxb  = (float*)(ws + (size_t)50331648);
  float* hb    = (float*)(ws + 0);                      // 8192x2048 overlaps q..ctx
  float* ctxln = (float*)(ws + (size_t)67108864);
  float* ymoe  = (float*)(ws + (size_t)83886080);
  char*  small = ws + (size_t)100663296;
  int*   idx0  = (int*)(small + 0);
  int*   idx1  = (int*)(small + 32768);
  float* w0a   = (float*)(small + 65536);
  float* w1a   = (float*)(small + 98304);
  int*   lrow  = (int*)(small + 131072);
  float* lwv   = (float*)(small + 198656);
  int*   cnts  = (int*)(small + 266240);

  dim3 blk(256);
  // QKV projections
  gemm64<<<dim3(8, 128), blk, 0, stream>>>(x, wq, qb, nullptr, NTOK, DM, DM, 0);
  gemm64<<<dim3(8, 128), blk, 0, stream>>>(x, wk, kb, nullptr, NTOK, DM, DM, 0);
  gemm64<<<dim3(8, 128), blk, 0, stream>>>(x, wv, vb, nullptr, NTOK, DM, DM, 0);
  // attention
  attn_kernel<<<8192, blk, 0, stream>>>(qb, kb, vb, ctxb);
  // y0 = relu(ctx@wo) + x  (into q buffer)
  gemm64<<<dim3(8, 128), blk, 0, stream>>>(ctxb, wo, qb, x, NTOK, DM, DM, 1);
  // ctx_ln = LN(y0)
  ln_kernel<<<8192, blk, 0, stream>>>(qb, nullptr, ctxln, DM, 0,
      ln_attn_g, ln_attn_g, ln_attn_g, ln_attn_g, ln_attn_b, ln_attn_b, ln_attn_b, ln_attn_b);
  // gating
  gate1<<<2048, blk, 0, stream>>>(ctxln, wg1, idx0, idx1, w0a, w1a);
  gate2<<<96, 64, 0, stream>>>(idx0, idx1, w0a, w1a, lrow, lwv, cnts);
  // zero accumulators
  hipMemsetAsync(hb, 0, (size_t)NTOK * DI * 4, stream);
  hipMemsetAsync(ymoe, 0, (size_t)NTOK * DM * 4, stream);
  // MoE layer 1: h += w * (x@W1[e] + b1[e])
  moe_gemm<<<dim3(32, 3, 96), blk, 0, stream>>>(ctxln, w1, b1, lrow, lwv, cnts, hb, DM, DI);
  // h = relu(LN_g(h)) per-group
  ln_kernel<<<8192, blk, 0, stream>>>(hb, nullptr, hb, DI, 1,
      ln1g, ln2g, ln3g, ln4g, ln1b, ln2b, ln3b, ln4b);
  // MoE layer 2: ymoe += w * (h@W2[e] + b2[e])
  moe_gemm<<<dim3(8, 3, 96), blk, 0, stream>>>(hb, w2, b2, lrow, lwv, cnts, ymoe, DI, DM);
  // out = LN(ymoe + resid)
  ln_kernel<<<8192, blk, 0, stream>>>(ymoe, ctxln, (float*)d_out, DM, 0,
      ln_out_g, ln_out_g, ln_out_g, ln_out_g, ln_out_b, ln_out_b, ln_out_b, ln_out_b);
}

// Round 2
// 1829.011 us; speedup vs baseline: 2.2292x; 2.2292x over previous
//
#include <hip/hip_runtime.h>
#include <cstdint>

#define NTOK 8192
#define DM   512
#define DI   2048
#define NEXP 24
#define TPG  2048
#define CAP  171
#define CAPR 176
#define EPSF 1e-6f

typedef __bf16 bf16x8 __attribute__((ext_vector_type(8)));
typedef float f32x4 __attribute__((ext_vector_type(4)));

static __device__ __forceinline__ unsigned short f2bf(float f) {
  unsigned int u = __builtin_bit_cast(unsigned int, f);
  u = (u + 0x7fffu + ((u >> 16) & 1u)) >> 16;
  return (unsigned short)u;
}

// ---------------- generic 64x64 tiled GEMM
// mode 0: C = A@B (fp32) ; mode 1: C = relu(A@B) + Add (fp32) ; mode 2: Cb = bf16(scale * A@B)
__global__ __launch_bounds__(256) void gemm64(
    const float* __restrict__ A, const float* __restrict__ B, float* __restrict__ C,
    unsigned short* __restrict__ Cb, const float* __restrict__ Add,
    int M, int N, int K, int mode, float scale)
{
  __shared__ float As[16][64];
  __shared__ float Bs[16][64];
  int tid = threadIdx.x;
  int m0 = blockIdx.y * 64, n0 = blockIdx.x * 64;
  int tm = tid & 15, tn = tid >> 4;
  int arow = tid >> 2, ac4 = tid & 3;
  int bkk = tid >> 4, bc4 = tid & 15;
  const float* aptr = A + (size_t)(m0 + arow) * K + ac4 * 4;
  const float* bptr = B + (size_t)bkk * N + n0 + bc4 * 4;
  float acc[4][4] = {};
  for (int k0 = 0; k0 < K; k0 += 16) {
    float4 av = *(const float4*)(aptr + k0);
    float4 bv = *(const float4*)(bptr + (size_t)k0 * N);
    __syncthreads();
    As[ac4*4+0][arow] = av.x;
    As[ac4*4+1][arow] = av.y;
    As[ac4*4+2][arow] = av.z;
    As[ac4*4+3][arow] = av.w;
    *(float4*)&Bs[bkk][bc4*4] = bv;
    __syncthreads();
    #pragma unroll
    for (int kk = 0; kk < 16; ++kk) {
      float4 a = *(const float4*)&As[kk][tm*4];
      float4 b = *(const float4*)&Bs[kk][tn*4];
      acc[0][0] += a.x*b.x; acc[0][1] += a.x*b.y; acc[0][2] += a.x*b.z; acc[0][3] += a.x*b.w;
      acc[1][0] += a.y*b.x; acc[1][1] += a.y*b.y; acc[1][2] += a.y*b.z; acc[1][3] += a.y*b.w;
      acc[2][0] += a.z*b.x; acc[2][1] += a.z*b.y; acc[2][2] += a.z*b.z; acc[2][3] += a.z*b.w;
      acc[3][0] += a.w*b.x; acc[3][1] += a.w*b.y; acc[3][2] += a.w*b.z; acc[3][3] += a.w*b.w;
    }
  }
  #pragma unroll
  for (int i = 0; i < 4; ++i) {
    int m = m0 + tm*4 + i;
    if (mode == 2) {
      unsigned short* cb = Cb + (size_t)m * N + n0 + tn*4;
      ushort4 u;
      u.x = f2bf(acc[i][0] * scale);
      u.y = f2bf(acc[i][1] * scale);
      u.z = f2bf(acc[i][2] * scale);
      u.w = f2bf(acc[i][3] * scale);
      *(ushort4*)cb = u;
    } else {
      float* cp = C + (size_t)m * N + n0 + tn*4;
      const float* ap2 = Add ? (Add + (size_t)m * N + n0 + tn*4) : nullptr;
      #pragma unroll
      for (int j = 0; j < 4; ++j) {
        float c = acc[i][j];
        if (mode == 1) c = fmaxf(c, 0.0f) + ap2[j];
        cp[j] = c;
      }
    }
  }
}

// ---------------- MFMA bf16 flash attention
// grid (16 qtiles, 64 bh); block 256 = 4 waves; wave owns 16 q-rows; 64-key chunks.
__global__ __launch_bounds__(256) void attn_mfma(
    const unsigned short* __restrict__ Qb, const unsigned short* __restrict__ Kb,
    const unsigned short* __restrict__ Vb, float* __restrict__ ctx)
{
  __shared__ unsigned short Ks[64 * 72];      // K chunk row-major [key][d], pad 72
  __shared__ unsigned short Vt[64 * 72];      // V chunk transposed [d][key], pad 72
  __shared__ unsigned short Ps[4][16 * 72];   // per-wave P tile [q][key], pad 72
  int tid = threadIdx.x;
  int w = tid >> 6, lane = tid & 63, quad = lane >> 4, l16 = lane & 15;
  int qt = blockIdx.x, bh = blockIdx.y;
  int b = bh >> 3, h = bh & 7;
  size_t hoff = (size_t)h * 64;
  size_t tokbase = (size_t)b * 1024;

  // Q A-frags: lane holds Q[q = l16][d = quad*8+j (+32)], q already scaled by 1/8 at projection
  int qrow = qt * 64 + w * 16 + l16;
  const unsigned short* qp = Qb + (tokbase + qrow) * 512 + hoff + quad * 8;
  bf16x8 qa0 = *(const bf16x8*)(qp);
  bf16x8 qa1 = *(const bf16x8*)(qp + 32);

  f32x4 O[4] = {};
  float mrow[4], lrow[4];
  #pragma unroll
  for (int r = 0; r < 4; ++r) { mrow[r] = -1e30f; lrow[r] = 0.f; }

  for (int kv0 = 0; kv0 < 1024; kv0 += 64) {
    __syncthreads();
    // stage K chunk (coalesced copy)
    {
      const unsigned short* kg = Kb + (tokbase + kv0) * 512 + hoff;
      #pragma unroll
      for (int i = 0; i < 2; ++i) {
        int f = tid + i * 256;          // 512 x 16B units
        int key = f >> 3, c = f & 7;
        *(uint4*)&Ks[key * 72 + c * 8] = *(const uint4*)(kg + (size_t)key * 512 + c * 8);
      }
      // stage V transposed: lanes vary d (contiguous) -> coalesced rows
      const unsigned short* vg = Vb + (tokbase + kv0) * 512 + hoff;
      int d = tid & 63;
      #pragma unroll
      for (int i = 0; i < 2; ++i) {
        int ko = (tid >> 6) + i * 4;    // key octet 0..7
        const unsigned short* vq = vg + (size_t)ko * 8 * 512 + d;
        unsigned int a0 = vq[0],        a1 = vq[512];
        unsigned int a2 = vq[2 * 512],  a3 = vq[3 * 512];
        unsigned int a4 = vq[4 * 512],  a5 = vq[5 * 512];
        unsigned int a6 = vq[6 * 512],  a7 = vq[7 * 512];
        uint4 pk;
        pk.x = a0 | (a1 << 16); pk.y = a2 | (a3 << 16);
        pk.z = a4 | (a5 << 16); pk.w = a6 | (a7 << 16);
        *(uint4*)&Vt[d * 72 + ko * 8] = pk;
      }
    }
    __syncthreads();

    // S = Q @ K^T : 4 key subtiles of 16
    f32x4 s[4];
    #pragma unroll
    for (int kt = 0; kt < 4; ++kt) {
      const unsigned short* kr = &Ks[(kt * 16 + l16) * 72 + quad * 8];
      bf16x8 kb0 = *(const bf16x8*)(kr);
      bf16x8 kb1 = *(const bf16x8*)(kr + 32);
      f32x4 z = {};
      z = __builtin_amdgcn_mfma_f32_16x16x32_bf16(qa0, kb0, z, 0, 0, 0);
      z = __builtin_amdgcn_mfma_f32_16x16x32_bf16(qa1, kb1, z, 0, 0, 0);
      s[kt] = z;
    }

    // online softmax; row r lives in the 16-lane col group (shfl butterfly over 1,2,4,8)
    #pragma unroll
    for (int r = 0; r < 4; ++r) {
      float mx = fmaxf(fmaxf(s[0][r], s[1][r]), fmaxf(s[2][r], s[3][r]));
      mx = fmaxf(mx, __shfl_xor(mx, 1, 64));
      mx = fmaxf(mx, __shfl_xor(mx, 2, 64));
      mx = fmaxf(mx, __shfl_xor(mx, 4, 64));
      mx = fmaxf(mx, __shfl_xor(mx, 8, 64));
      float mnew = fmaxf(mrow[r], mx);
      float alpha = __expf(mrow[r] - mnew);
      mrow[r] = mnew;
      float psum = 0.f;
      #pragma unroll
      for (int kt = 0; kt < 4; ++kt) {
        float p = __expf(s[kt][r] - mnew);
        s[kt][r] = p;
        psum += p;
      }
      psum += __shfl_xor(psum, 1, 64);
      psum += __shfl_xor(psum, 2, 64);
      psum += __shfl_xor(psum, 4, 64);
      psum += __shfl_xor(psum, 8, 64);
      lrow[r] = lrow[r] * alpha + psum;
      #pragma unroll
      for (int dt = 0; dt < 4; ++dt) O[dt][r] *= alpha;
    }

    // P: C-layout -> LDS -> A-layout (per-wave region, no barrier needed)
    #pragma unroll
    for (int kt = 0; kt < 4; ++kt)
      #pragma unroll
      for (int r = 0; r < 4; ++r)
        Ps[w][(quad * 4 + r) * 72 + kt * 16 + l16] = f2bf(s[kt][r]);
    const unsigned short* pp = &Ps[w][l16 * 72 + quad * 8];
    bf16x8 pa0 = *(const bf16x8*)(pp);
    bf16x8 pa1 = *(const bf16x8*)(pp + 32);

    // O += P @ V
    #pragma unroll
    for (int dt = 0; dt < 4; ++dt) {
      const unsigned short* vr = &Vt[(dt * 16 + l16) * 72 + quad * 8];
      bf16x8 vb0 = *(const bf16x8*)(vr);
      bf16x8 vb1 = *(const bf16x8*)(vr + 32);
      O[dt] = __builtin_amdgcn_mfma_f32_16x16x32_bf16(pa0, vb0, O[dt], 0, 0, 0);
      O[dt] = __builtin_amdgcn_mfma_f32_16x16x32_bf16(pa1, vb1, O[dt], 0, 0, 0);
    }
  }

  #pragma unroll
  for (int r = 0; r < 4; ++r) {
    float inv = 1.0f / lrow[r];
    int row = qt * 64 + w * 16 + quad * 4 + r;
    float* cp = ctx + (tokbase + row) * 512 + hoff + l16;
    #pragma unroll
    for (int dt = 0; dt < 4; ++dt) cp[dt * 16] = O[dt][r] * inv;
  }
}

// ---------------- layernorm (optional pre-add and post-relu; per-group gamma/beta select)
__global__ __launch_bounds__(256) void ln_kernel(
    const float* __restrict__ in, const float* __restrict__ add, float* __restrict__ out,
    int D, int relu_after,
    const float* __restrict__ g0, const float* __restrict__ g1,
    const float* __restrict__ g2, const float* __restrict__ g3,
    const float* __restrict__ bb0, const float* __restrict__ bb1,
    const float* __restrict__ bb2, const float* __restrict__ bb3)
{
  int row = blockIdx.x;
  int grp = (row & 1023) >> 8;
  const float* g  = grp == 0 ? g0  : grp == 1 ? g1  : grp == 2 ? g2  : g3;
  const float* bb = grp == 0 ? bb0 : grp == 1 ? bb1 : grp == 2 ? bb2 : bb3;
  const float* ip = in + (size_t)row * D;
  const float* ap = add ? add + (size_t)row * D : nullptr;
  float vals[8];
  int per = D >> 8;
  float s1 = 0.f, s2 = 0.f;
  for (int i = 0; i < per; ++i) {
    int d = threadIdx.x + (i << 8);
    float vv = ip[d];
    if (ap) vv += ap[d];
    vals[i] = vv; s1 += vv; s2 += vv * vv;
  }
  #pragma unroll
  for (int o = 32; o; o >>= 1) { s1 += __shfl_xor(s1, o, 64); s2 += __shfl_xor(s2, o, 64); }
  __shared__ float sA[4], sB[4];
  int wid = threadIdx.x >> 6, lane = threadIdx.x & 63;
  if (lane == 0) { sA[wid] = s1; sB[wid] = s2; }
  __syncthreads();
  float t1 = sA[0] + sA[1] + sA[2] + sA[3];
  float t2 = sB[0] + sB[1] + sB[2] + sB[3];
  float mean = t1 / (float)D;
  float var = t2 / (float)D - mean * mean;
  float rs = rsqrtf(var + EPSF);
  float* op = out + (size_t)row * D;
  for (int i = 0; i < per; ++i) {
    int d = threadIdx.x + (i << 8);
    float o = (vals[i] - mean) * rs * g[d] + bb[d];
    if (relu_after) o = fmaxf(o, 0.f);
    op[d] = o;
  }
}

// ---------------- gating stage 1: per-token logits + top2 (normalized weights)
__global__ __launch_bounds__(256) void gate1(
    const float* __restrict__ xln, const float* __restrict__ wg,
    int* __restrict__ idx0, int* __restrict__ idx1,
    float* __restrict__ w0o, float* __restrict__ w1o)
{
  int wid = threadIdx.x >> 6, lane = threadIdx.x & 63;
  int tk = blockIdx.x * 4 + wid;            // 0..8191
  int g = tk >> 11, t = tk & 2047;
  int b = t >> 8, j = t & 255;
  size_t row = (size_t)b * 1024 + g * 256 + j;
  const float* xp = xln + row * 512;
  float acc = -1e30f;
  if (lane < 24) {
    acc = 0.f;
    for (int d = 0; d < 512; ++d) acc += xp[d] * wg[d * 24 + lane];
  }
  float b0v = -1e30f, b1v = -1e30f; int i0 = 0, i1 = 0;
  for (int e = 0; e < 24; ++e) {
    float vv = __shfl(acc, e, 64);
    if (vv > b0v)      { b1v = b0v; i1 = i0; b0v = vv; i0 = e; }
    else if (vv > b1v) { b1v = vv; i1 = e; }
  }
  if (lane == 0) {
    float w0 = 1.0f / (1.0f + __expf(b1v - b0v));  // softmax denom cancels in w/sum(w)
    idx0[tk] = i0; idx1[tk] = i1; w0o[tk] = w0; w1o[tk] = 1.0f - w0;
  }
}

// ---------------- gating stage 2: capacity-limited ranking -> per-(g,e) token lists
__global__ __launch_bounds__(64) void gate2(
    const int* __restrict__ idx0, const int* __restrict__ idx1,
    const float* __restrict__ w0, const float* __restrict__ w1,
    int* __restrict__ lrow, float* __restrict__ lw, int* __restrict__ counts)
{
  int pair = blockIdx.x; int g = pair / 24; int e = pair % 24;
  int lane = threadIdx.x;
  int base = g * TPG;
  unsigned long long lm = (lane == 63) ? 0x7fffffffffffffffULL : ((1ULL << lane) - 1ULL);
  int run = 0;
  for (int it = 0; it < TPG / 64; ++it) {
    int t = it * 64 + lane;
    bool m = (idx0[base + t] == e);
    unsigned long long mask = __ballot(m);
    int pre = __popcll(mask & lm);
    int rank = run + pre;
    if (m && rank < CAP) {
      int bq = t >> 8, j = t & 255;
      lrow[pair * CAPR + rank] = bq * 1024 + g * 256 + j;
      lw[pair * CAPR + rank] = w0[base + t];
    }
    run += __popcll(mask);
  }
  int total1 = run;
  int run2 = 0;
  for (int it = 0; it < TPG / 64; ++it) {
    int t = it * 64 + lane;
    bool m = (idx1[base + t] == e);
    unsigned long long mask = __ballot(m);
    int pre = __popcll(mask & lm);
    int rank2 = run2 + pre;
    if (m && (total1 + rank2) < CAP) {
      int bq = t >> 8, j = t & 255;
      lrow[pair * CAPR + total1 + rank2] = bq * 1024 + g * 256 + j;
      lw[pair * CAPR + total1 + rank2] = w1[base + t];
    }
    run2 += __popcll(mask);
  }
  if (lane == 0) {
    int c1 = total1 < CAP ? total1 : CAP;
    int room = CAP - total1; if (room < 0) room = 0;
    int c2 = run2 < room ? run2 : room;
    counts[pair] = c1 + c2;
  }
}

// ---------------- MoE expert GEMM over gathered token list; atomic weighted combine
__global__ __launch_bounds__(256) void moe_gemm(
    const float* __restrict__ X, const float* __restrict__ W, const float* __restrict__ bias,
    const int* __restrict__ lrow, const float* __restrict__ lw, const int* __restrict__ counts,
    float* __restrict__ Out, int K, int N)
{
  int pair = blockIdx.z;
  int e = pair % 24;
  int count = counts[pair];
  int m0 = blockIdx.y * 64;
  if (m0 >= count) return;
  int n0 = blockIdx.x * 64;
  __shared__ float As[16][64];
  __shared__ float Bs[16][64];
  int tid = threadIdx.x;
  int tm = tid & 15, tn = tid >> 4;
  int arow = tid >> 2, ac4 = tid & 3;
  int am = m0 + arow;
  int srow = lrow[pair * CAPR + (am < count ? am : 0)];
  const float* aptr = X + (size_t)srow * K + ac4 * 4;
  int bkk = tid >> 4, bc4 = tid & 15;
  const float* bptr = W + ((size_t)e * K + bkk) * N + n0 + bc4 * 4;
  float acc[4][4] = {};
  for (int k0 = 0; k0 < K; k0 += 16) {
    float4 av = *(const float4*)(aptr + k0);
    float4 bv = *(const float4*)(bptr + (size_t)k0 * N);
    __syncthreads();
    As[ac4*4+0][arow] = av.x;
    As[ac4*4+1][arow] = av.y;
    As[ac4*4+2][arow] = av.z;
    As[ac4*4+3][arow] = av.w;
    *(float4*)&Bs[bkk][bc4*4] = bv;
    __syncthreads();
    #pragma unroll
    for (int kk = 0; kk < 16; ++kk) {
      float4 a = *(const float4*)&As[kk][tm*4];
      float4 b = *(const float4*)&Bs[kk][tn*4];
      acc[0][0] += a.x*b.x; acc[0][1] += a.x*b.y; acc[0][2] += a.x*b.z; acc[0][3] += a.x*b.w;
      acc[1][0] += a.y*b.x; acc[1][1] += a.y*b.y; acc[1][2] += a.y*b.z; acc[1][3] += a.y*b.w;
      acc[2][0] += a.z*b.x; acc[2][1] += a.z*b.y; acc[2][2] += a.z*b.z; acc[2][3] += a.z*b.w;
      acc[3][0] += a.w*b.x; acc[3][1] += a.w*b.y; acc[3][2] += a.w*b.z; acc[3][3] += a.w*b.w;
    }
  }
  float4 biv = *(const float4*)(bias + (size_t)e * N + n0 + tn * 4);
  #pragma unroll
  for (int i = 0; i < 4; ++i) {
    int m = m0 + tm * 4 + i;
    if (m < count) {
      int r = lrow[pair * CAPR + m];
      float w = lw[pair * CAPR + m];
      float* op = Out + (size_t)r * N + n0 + tn * 4;
      atomicAdd(&op[0], w * (acc[i][0] + biv.x));
      atomicAdd(&op[1], w * (acc[i][1] + biv.y));
      atomicAdd(&op[2], w * (acc[i][2] + biv.z));
      atomicAdd(&op[3], w * (acc[i][3] + biv.w));
    }
  }
}

extern "C" void kernel_launch(void* const* d_in, const int* in_sizes, int n_in,
                              void* d_out, int out_size, void* d_ws, size_t ws_size,
                              hipStream_t stream)
{
  const float* x   = (const float*)d_in[0];
  const float* wq  = (const float*)d_in[1];
  const float* wk  = (const float*)d_in[2];
  const float* wv  = (const float*)d_in[3];
  const float* wo  = (const float*)d_in[4];
  const float* ln_attn_g = (const float*)d_in[5];
  const float* ln_attn_b = (const float*)d_in[6];
  const float* wg1 = (const float*)d_in[7];
  const float* w1  = (const float*)d_in[8];
  const float* b1  = (const float*)d_in[9];
  /* d_in[10] = wg2 — unused by reference (routing reused for both MoE layers) */
  const float* w2  = (const float*)d_in[11];
  const float* b2  = (const float*)d_in[12];
  const float* ln_out_g = (const float*)d_in[13];
  const float* ln_out_b = (const float*)d_in[14];
  const float* ln1g = (const float*)d_in[15]; const float* ln1b = (const float*)d_in[16];
  const float* ln2g = (const float*)d_in[17]; const float* ln2b = (const float*)d_in[18];
  const float* ln3g = (const float*)d_in[19]; const float* ln3b = (const float*)d_in[20];
  const float* ln4g = (const float*)d_in[21]; const float* ln4b = (const float*)d_in[22];

  char* ws = (char*)d_ws;
  unsigned short* qbf = (unsigned short*)(ws + 0);               // 8 MB
  unsigned short* kbf = (unsigned short*)(ws + (size_t)8388608); // 8 MB
  unsigned short* vbf = (unsigned short*)(ws + (size_t)16777216);// 8 MB
  float* ctxb  = (float*)(ws + (size_t)25165824);                // 16 MB
  float* y0    = (float*)(ws + (size_t)41943040);                // 16 MB
  float* hb    = (float*)(ws + 0);                               // 64 MB, overlaps dead qkv/ctx/y0
  float* ctxln = (float*)(ws + (size_t)67108864);                // 16 MB
  float* ymoe  = (float*)(ws + (size_t)83886080);                // 16 MB
  char*  small = ws + (size_t)100663296;
  int*   idx0  = (int*)(small + 0);
  int*   idx1  = (int*)(small + 32768);
  float* w0a   = (float*)(small + 65536);
  float* w1a   = (float*)(small + 98304);
  int*   lrowp = (int*)(small + 131072);
  float* lwv   = (float*)(small + 198656);
  int*   cnts  = (int*)(small + 266240);

  dim3 blk(256);
  // QKV projections -> bf16 (q pre-scaled by 1/sqrt(dk) = 0.125, exact in bf16)
  gemm64<<<dim3(8, 128), blk, 0, stream>>>(x, wq, nullptr, qbf, nullptr, NTOK, DM, DM, 2, 0.125f);
  gemm64<<<dim3(8, 128), blk, 0, stream>>>(x, wk, nullptr, kbf, nullptr, NTOK, DM, DM, 2, 1.0f);
  gemm64<<<dim3(8, 128), blk, 0, stream>>>(x, wv, nullptr, vbf, nullptr, NTOK, DM, DM, 2, 1.0f);
  // MFMA flash attention
  attn_mfma<<<dim3(16, 64), blk, 0, stream>>>(qbf, kbf, vbf, ctxb);
  // y0 = relu(ctx@wo) + x
  gemm64<<<dim3(8, 128), blk, 0, stream>>>(ctxb, wo, y0, nullptr, x, NTOK, DM, DM, 1, 1.0f);
  // ctx_ln = LN(y0)
  ln_kernel<<<8192, blk, 0, stream>>>(y0, nullptr, ctxln, DM, 0,
      ln_attn_g, ln_attn_g, ln_attn_g, ln_attn_g, ln_attn_b, ln_attn_b, ln_attn_b, ln_attn_b);
  // gating
  gate1<<<2048, blk, 0, stream>>>(ctxln, wg1, idx0, idx1, w0a, w1a);
  gate2<<<96, 64, 0, stream>>>(idx0, idx1, w0a, w1a, lrowp, lwv, cnts);
  // zero accumulators
  hipMemsetAsync(hb, 0, (size_t)NTOK * DI * 4, stream);
  hipMemsetAsync(ymoe, 0, (size_t)NTOK * DM * 4, stream);
  // MoE layer 1
  moe_gemm<<<dim3(32, 3, 96), blk, 0, stream>>>(ctxln, w1, b1, lrowp, lwv, cnts, hb, DM, DI);
  // h = relu(LN_g(h)) per-group
  ln_kernel<<<8192, blk, 0, stream>>>(hb, nullptr, hb, DI, 1,
      ln1g, ln2g, ln3g, ln4g, ln1b, ln2b, ln3b, ln4b);
  // MoE layer 2
  moe_gemm<<<dim3(8, 3, 96), blk, 0, stream>>>(hb, w2, b2, lrowp, lwv, cnts, ymoe, DI, DM);
  // out = LN(ymoe + resid)
  ln_kernel<<<8192, blk, 0, stream>>>(ymoe, ctxln, (float*)d_out, DM, 0,
      ln_out_g, ln_out_g, ln_out_g, ln_out_g, ln_out_b, ln_out_b, ln_out_b, ln_out_b);
}

// Round 3
// 951.427 us; speedup vs baseline: 4.2853x; 1.9224x over previous
//
#include <hip/hip_runtime.h>
#include <cstdint>

#define NTOK 8192
#define DM   512
#define DI   2048
#define NEXP 24
#define TPG  2048
#define CAP  171
#define CAPR 176
#define EPSF 1e-6f

typedef __bf16 bf16x8 __attribute__((ext_vector_type(8)));
typedef float f32x4 __attribute__((ext_vector_type(4)));

static __device__ __forceinline__ unsigned short f2bf(float f) {
  unsigned int u = __builtin_bit_cast(unsigned int, f);
  u = (u + 0x7fffu + ((u >> 16) & 1u)) >> 16;
  return (unsigned short)u;
}
static __device__ __forceinline__ unsigned int pk2(float a, float b) {
  return (unsigned int)f2bf(a) | ((unsigned int)f2bf(b) << 16);
}

// ---------------- unified bf16-MFMA GEMM, 64m x 128n tile, BK=64, 4 waves
// A: fp32 rows [*, lda], optionally gathered via lrow (pair*CAPR+m)
// B: fp32 [e][K][N] — transposed+converted to bf16 during LDS staging
// mode 0: Cb[m*N+col] = bf16(acc*scale)
// mode 1: Cf[m*N+col] = relu(acc) + Add[m*N+col]
// mode 2: atomicAdd(Cf[lrow[m]*N+col], lw[m]*(acc + bias[e*N+col]))
__global__ __launch_bounds__(256) void mfma_gemm(
    const float* __restrict__ A, int lda,
    const float* __restrict__ Bf,
    const float* __restrict__ bias,
    const int* __restrict__ lrow, const float* __restrict__ lw,
    const int* __restrict__ cnts,
    float* __restrict__ Cf, unsigned short* __restrict__ Cb,
    const float* __restrict__ Add,
    int M, int N, int K, int mode, float scale)
{
  __shared__ unsigned short As[64 * 72];
  __shared__ unsigned short Bs[128 * 72];
  int tid = threadIdx.x;
  int w = tid >> 6, lane = tid & 63, quad = lane >> 4, l16 = lane & 15;
  int n0 = blockIdx.x * 128;
  int m0 = blockIdx.y * 64;
  int pair = blockIdx.z;
  int e = pair % NEXP;
  int count = cnts ? cnts[pair] : M;
  if (m0 >= count) return;
  const int*   lr  = lrow ? lrow + pair * CAPR : nullptr;
  const float* lwp = lw   ? lw   + pair * CAPR : nullptr;
  const float* Bfe = Bf + (size_t)e * K * N;

  // A staging rows (2 packs/thread, fixed m)
  const float* aptr[2];
  #pragma unroll
  for (int i = 0; i < 2; ++i) {
    int p = tid + i * 256;
    int m = p >> 3, kg = p & 7;
    int mm = m0 + m; if (mm >= count) mm = count - 1;
    int rm = lr ? lr[mm] : mm;
    aptr[i] = A + (size_t)rm * lda + kg * 8;
  }
  int bn = tid & 127, bkg0 = tid >> 7;

  f32x4 acc[4][2] = {};
  for (int k0 = 0; k0 < K; k0 += 64) {
    __syncthreads();
    // ---- A: fp32 -> bf16, [m][k] (pad 72)
    #pragma unroll
    for (int i = 0; i < 2; ++i) {
      int p = tid + i * 256;
      int m = p >> 3, kg = p & 7;
      float4 v0 = *(const float4*)(aptr[i] + k0);
      float4 v1 = *(const float4*)(aptr[i] + k0 + 4);
      uint4 pk;
      pk.x = pk2(v0.x, v0.y); pk.y = pk2(v0.z, v0.w);
      pk.z = pk2(v1.x, v1.y); pk.w = pk2(v1.z, v1.w);
      *(uint4*)&As[m * 72 + kg * 8] = pk;
    }
    // ---- B: fp32 [k][n] -> bf16 [n][k] (transpose during gather)
    #pragma unroll
    for (int i = 0; i < 4; ++i) {
      int kg = bkg0 + i * 2;
      const float* q = Bfe + (size_t)(k0 + kg * 8) * N + n0 + bn;
      float b0 = q[0];            float b1 = q[(size_t)N];
      float b2 = q[(size_t)2*N];  float b3 = q[(size_t)3*N];
      float b4 = q[(size_t)4*N];  float b5 = q[(size_t)5*N];
      float b6 = q[(size_t)6*N];  float b7 = q[(size_t)7*N];
      uint4 pk;
      pk.x = pk2(b0, b1); pk.y = pk2(b2, b3);
      pk.z = pk2(b4, b5); pk.w = pk2(b6, b7);
      *(uint4*)&Bs[bn * 72 + kg * 8] = pk;
    }
    __syncthreads();
    // ---- MFMA
    #pragma unroll
    for (int half = 0; half < 2; ++half) {
      bf16x8 af[4];
      #pragma unroll
      for (int ms = 0; ms < 4; ++ms)
        af[ms] = *(const bf16x8*)&As[(ms * 16 + l16) * 72 + half * 32 + quad * 8];
      bf16x8 bfr[2];
      #pragma unroll
      for (int ns = 0; ns < 2; ++ns)
        bfr[ns] = *(const bf16x8*)&Bs[(w * 32 + ns * 16 + l16) * 72 + half * 32 + quad * 8];
      #pragma unroll
      for (int ms = 0; ms < 4; ++ms)
        #pragma unroll
        for (int ns = 0; ns < 2; ++ns)
          acc[ms][ns] = __builtin_amdgcn_mfma_f32_16x16x32_bf16(af[ms], bfr[ns], acc[ms][ns], 0, 0, 0);
    }
  }
  // ---- epilogue
  float bv[2];
  if (mode == 2) {
    #pragma unroll
    for (int ns = 0; ns < 2; ++ns)
      bv[ns] = bias[(size_t)e * N + n0 + w * 32 + ns * 16 + l16];
  }
  #pragma unroll
  for (int ms = 0; ms < 4; ++ms) {
    #pragma unroll
    for (int ns = 0; ns < 2; ++ns) {
      int col = n0 + w * 32 + ns * 16 + l16;
      #pragma unroll
      for (int r = 0; r < 4; ++r) {
        int m = m0 + ms * 16 + quad * 4 + r;
        if (mode == 0) {
          Cb[(size_t)m * N + col] = f2bf(acc[ms][ns][r] * scale);
        } else if (mode == 1) {
          Cf[(size_t)m * N + col] = fmaxf(acc[ms][ns][r], 0.f) + Add[(size_t)m * N + col];
        } else {
          if (m < count) {
            int rr = lr[m];
            float wgt = lwp[m];
            atomicAdd(&Cf[(size_t)rr * N + col], wgt * (acc[ms][ns][r] + bv[ns]));
          }
        }
      }
    }
  }
}

// ---------------- MFMA bf16 flash attention (unchanged from R2, verified)
__global__ __launch_bounds__(256) void attn_mfma(
    const unsigned short* __restrict__ Qb, const unsigned short* __restrict__ Kb,
    const unsigned short* __restrict__ Vb, float* __restrict__ ctx)
{
  __shared__ unsigned short Ks[64 * 72];
  __shared__ unsigned short Vt[64 * 72];
  __shared__ unsigned short Ps[4][16 * 72];
  int tid = threadIdx.x;
  int w = tid >> 6, lane = tid & 63, quad = lane >> 4, l16 = lane & 15;
  int qt = blockIdx.x, bh = blockIdx.y;
  int b = bh >> 3, h = bh & 7;
  size_t hoff = (size_t)h * 64;
  size_t tokbase = (size_t)b * 1024;

  int qrow = qt * 64 + w * 16 + l16;
  const unsigned short* qp = Qb + (tokbase + qrow) * 512 + hoff + quad * 8;
  bf16x8 qa0 = *(const bf16x8*)(qp);
  bf16x8 qa1 = *(const bf16x8*)(qp + 32);

  f32x4 O[4] = {};
  float mrow[4], lrowv[4];
  #pragma unroll
  for (int r = 0; r < 4; ++r) { mrow[r] = -1e30f; lrowv[r] = 0.f; }

  for (int kv0 = 0; kv0 < 1024; kv0 += 64) {
    __syncthreads();
    {
      const unsigned short* kg = Kb + (tokbase + kv0) * 512 + hoff;
      #pragma unroll
      for (int i = 0; i < 2; ++i) {
        int f = tid + i * 256;
        int key = f >> 3, c = f & 7;
        *(uint4*)&Ks[key * 72 + c * 8] = *(const uint4*)(kg + (size_t)key * 512 + c * 8);
      }
      const unsigned short* vg = Vb + (tokbase + kv0) * 512 + hoff;
      int d = tid & 63;
      #pragma unroll
      for (int i = 0; i < 2; ++i) {
        int ko = (tid >> 6) + i * 4;
        const unsigned short* vq = vg + (size_t)ko * 8 * 512 + d;
        unsigned int a0 = vq[0],        a1 = vq[512];
        unsigned int a2 = vq[2 * 512],  a3 = vq[3 * 512];
        unsigned int a4 = vq[4 * 512],  a5 = vq[5 * 512];
        unsigned int a6 = vq[6 * 512],  a7 = vq[7 * 512];
        uint4 pk;
        pk.x = a0 | (a1 << 16); pk.y = a2 | (a3 << 16);
        pk.z = a4 | (a5 << 16); pk.w = a6 | (a7 << 16);
        *(uint4*)&Vt[d * 72 + ko * 8] = pk;
      }
    }
    __syncthreads();

    f32x4 s[4];
    #pragma unroll
    for (int kt = 0; kt < 4; ++kt) {
      const unsigned short* kr = &Ks[(kt * 16 + l16) * 72 + quad * 8];
      bf16x8 kb0 = *(const bf16x8*)(kr);
      bf16x8 kb1 = *(const bf16x8*)(kr + 32);
      f32x4 z = {};
      z = __builtin_amdgcn_mfma_f32_16x16x32_bf16(qa0, kb0, z, 0, 0, 0);
      z = __builtin_amdgcn_mfma_f32_16x16x32_bf16(qa1, kb1, z, 0, 0, 0);
      s[kt] = z;
    }

    #pragma unroll
    for (int r = 0; r < 4; ++r) {
      float mx = fmaxf(fmaxf(s[0][r], s[1][r]), fmaxf(s[2][r], s[3][r]));
      mx = fmaxf(mx, __shfl_xor(mx, 1, 64));
      mx = fmaxf(mx, __shfl_xor(mx, 2, 64));
      mx = fmaxf(mx, __shfl_xor(mx, 4, 64));
      mx = fmaxf(mx, __shfl_xor(mx, 8, 64));
      float mnew = fmaxf(mrow[r], mx);
      float alpha = __expf(mrow[r] - mnew);
      mrow[r] = mnew;
      float psum = 0.f;
      #pragma unroll
      for (int kt = 0; kt < 4; ++kt) {
        float p = __expf(s[kt][r] - mnew);
        s[kt][r] = p;
        psum += p;
      }
      psum += __shfl_xor(psum, 1, 64);
      psum += __shfl_xor(psum, 2, 64);
      psum += __shfl_xor(psum, 4, 64);
      psum += __shfl_xor(psum, 8, 64);
      lrowv[r] = lrowv[r] * alpha + psum;
      #pragma unroll
      for (int dt = 0; dt < 4; ++dt) O[dt][r] *= alpha;
    }

    #pragma unroll
    for (int kt = 0; kt < 4; ++kt)
      #pragma unroll
      for (int r = 0; r < 4; ++r)
        Ps[w][(quad * 4 + r) * 72 + kt * 16 + l16] = f2bf(s[kt][r]);
    const unsigned short* pp = &Ps[w][l16 * 72 + quad * 8];
    bf16x8 pa0 = *(const bf16x8*)(pp);
    bf16x8 pa1 = *(const bf16x8*)(pp + 32);

    #pragma unroll
    for (int dt = 0; dt < 4; ++dt) {
      const unsigned short* vr = &Vt[(dt * 16 + l16) * 72 + quad * 8];
      bf16x8 vb0 = *(const bf16x8*)(vr);
      bf16x8 vb1 = *(const bf16x8*)(vr + 32);
      O[dt] = __builtin_amdgcn_mfma_f32_16x16x32_bf16(pa0, vb0, O[dt], 0, 0, 0);
      O[dt] = __builtin_amdgcn_mfma_f32_16x16x32_bf16(pa1, vb1, O[dt], 0, 0, 0);
    }
  }

  #pragma unroll
  for (int r = 0; r < 4; ++r) {
    float inv = 1.0f / lrowv[r];
    int row = qt * 64 + w * 16 + quad * 4 + r;
    float* cp = ctx + (tokbase + row) * 512 + hoff + l16;
    #pragma unroll
    for (int dt = 0; dt < 4; ++dt) cp[dt * 16] = O[dt][r] * inv;
  }
}

// ---------------- layernorm (optional pre-add, post-relu, per-group params; in-place safe)
__global__ __launch_bounds__(256) void ln_kernel(
    const float* __restrict__ in, const float* __restrict__ add, float* __restrict__ out,
    int D, int relu_after,
    const float* __restrict__ g0, const float* __restrict__ g1,
    const float* __restrict__ g2, const float* __restrict__ g3,
    const float* __restrict__ bb0, const float* __restrict__ bb1,
    const float* __restrict__ bb2, const float* __restrict__ bb3)
{
  int row = blockIdx.x;
  int grp = (row & 1023) >> 8;
  const float* g  = grp == 0 ? g0  : grp == 1 ? g1  : grp == 2 ? g2  : g3;
  const float* bb = grp == 0 ? bb0 : grp == 1 ? bb1 : grp == 2 ? bb2 : bb3;
  const float* ip = in + (size_t)row * D;
  const float* ap = add ? add + (size_t)row * D : nullptr;
  float vals[8];
  int per = D >> 8;
  float s1 = 0.f, s2 = 0.f;
  for (int i = 0; i < per; ++i) {
    int d = threadIdx.x + (i << 8);
    float vv = ip[d];
    if (ap) vv += ap[d];
    vals[i] = vv; s1 += vv; s2 += vv * vv;
  }
  #pragma unroll
  for (int o = 32; o; o >>= 1) { s1 += __shfl_xor(s1, o, 64); s2 += __shfl_xor(s2, o, 64); }
  __shared__ float sA[4], sB[4];
  int wid = threadIdx.x >> 6, lane = threadIdx.x & 63;
  if (lane == 0) { sA[wid] = s1; sB[wid] = s2; }
  __syncthreads();
  float t1 = sA[0] + sA[1] + sA[2] + sA[3];
  float t2 = sB[0] + sB[1] + sB[2] + sB[3];
  float mean = t1 / (float)D;
  float var = t2 / (float)D - mean * mean;
  float rs = rsqrtf(var + EPSF);
  float* op = out + (size_t)row * D;
  for (int i = 0; i < per; ++i) {
    int d = threadIdx.x + (i << 8);
    float o = (vals[i] - mean) * rs * g[d] + bb[d];
    if (relu_after) o = fmaxf(o, 0.f);
    op[d] = o;
  }
}

// ---------------- gating stage 1
__global__ __launch_bounds__(256) void gate1(
    const float* __restrict__ xln, const float* __restrict__ wg,
    int* __restrict__ idx0, int* __restrict__ idx1,
    float* __restrict__ w0o, float* __restrict__ w1o)
{
  int wid = threadIdx.x >> 6, lane = threadIdx.x & 63;
  int tk = blockIdx.x * 4 + wid;
  int g = tk >> 11, t = tk & 2047;
  int b = t >> 8, j = t & 255;
  size_t row = (size_t)b * 1024 + g * 256 + j;
  const float* xp = xln + row * 512;
  float acc = -1e30f;
  if (lane < 24) {
    acc = 0.f;
    for (int d = 0; d < 512; ++d) acc += xp[d] * wg[d * 24 + lane];
  }
  float b0v = -1e30f, b1v = -1e30f; int i0 = 0, i1 = 0;
  for (int e = 0; e < 24; ++e) {
    float vv = __shfl(acc, e, 64);
    if (vv > b0v)      { b1v = b0v; i1 = i0; b0v = vv; i0 = e; }
    else if (vv > b1v) { b1v = vv; i1 = e; }
  }
  if (lane == 0) {
    float w0 = 1.0f / (1.0f + __expf(b1v - b0v));
    idx0[tk] = i0; idx1[tk] = i1; w0o[tk] = w0; w1o[tk] = 1.0f - w0;
  }
}

// ---------------- gating stage 2
__global__ __launch_bounds__(64) void gate2(
    const int* __restrict__ idx0, const int* __restrict__ idx1,
    const float* __restrict__ w0, const float* __restrict__ w1,
    int* __restrict__ lrow, float* __restrict__ lw, int* __restrict__ counts)
{
  int pair = blockIdx.x; int g = pair / 24; int e = pair % 24;
  int lane = threadIdx.x;
  int base = g * TPG;
  unsigned long long lm = (lane == 63) ? 0x7fffffffffffffffULL : ((1ULL << lane) - 1ULL);
  int run = 0;
  for (int it = 0; it < TPG / 64; ++it) {
    int t = it * 64 + lane;
    bool m = (idx0[base + t] == e);
    unsigned long long mask = __ballot(m);
    int pre = __popcll(mask & lm);
    int rank = run + pre;
    if (m && rank < CAP) {
      int bq = t >> 8, j = t & 255;
      lrow[pair * CAPR + rank] = bq * 1024 + g * 256 + j;
      lw[pair * CAPR + rank] = w0[base + t];
    }
    run += __popcll(mask);
  }
  int total1 = run;
  int run2 = 0;
  for (int it = 0; it < TPG / 64; ++it) {
    int t = it * 64 + lane;
    bool m = (idx1[base + t] == e);
    unsigned long long mask = __ballot(m);
    int pre = __popcll(mask & lm);
    int rank2 = run2 + pre;
    if (m && (total1 + rank2) < CAP) {
      int bq = t >> 8, j = t & 255;
      lrow[pair * CAPR + total1 + rank2] = bq * 1024 + g * 256 + j;
      lw[pair * CAPR + total1 + rank2] = w1[base + t];
    }
    run2 += __popcll(mask);
  }
  if (lane == 0) {
    int c1 = total1 < CAP ? total1 : CAP;
    int room = CAP - total1; if (room < 0) room = 0;
    int c2 = run2 < room ? run2 : room;
    counts[pair] = c1 + c2;
  }
}

extern "C" void kernel_launch(void* const* d_in, const int* in_sizes, int n_in,
                              void* d_out, int out_size, void* d_ws, size_t ws_size,
                              hipStream_t stream)
{
  const float* x   = (const float*)d_in[0];
  const float* wq  = (const float*)d_in[1];
  const float* wk  = (const float*)d_in[2];
  const float* wv  = (const float*)d_in[3];
  const float* wo  = (const float*)d_in[4];
  const float* ln_attn_g = (const float*)d_in[5];
  const float* ln_attn_b = (const float*)d_in[6];
  const float* wg1 = (const float*)d_in[7];
  const float* w1  = (const float*)d_in[8];
  const float* b1  = (const float*)d_in[9];
  const float* w2  = (const float*)d_in[11];
  const float* b2  = (const float*)d_in[12];
  const float* ln_out_g = (const float*)d_in[13];
  const float* ln_out_b = (const float*)d_in[14];
  const float* ln1g = (const float*)d_in[15]; const float* ln1b = (const float*)d_in[16];
  const float* ln2g = (const float*)d_in[17]; const float* ln2b = (const float*)d_in[18];
  const float* ln3g = (const float*)d_in[19]; const float* ln3b = (const float*)d_in[20];
  const float* ln4g = (const float*)d_in[21]; const float* ln4b = (const float*)d_in[22];

  char* ws = (char*)d_ws;
  // region 0..64 MB: qkv bf16 (0..24) + ctx fp32 (24..40) early; h fp32 later
  unsigned short* qbf = (unsigned short*)(ws + 0);
  unsigned short* kbf = (unsigned short*)(ws + (size_t)8388608);
  unsigned short* vbf = (unsigned short*)(ws + (size_t)16777216);
  float* ctxb  = (float*)(ws + (size_t)25165824);
  float* hb    = (float*)(ws + 0);                        // 64 MB
  float* y0    = (float*)(ws + (size_t)67108864);         // 16 MB; ymoe later
  float* ymoe  = (float*)(ws + (size_t)67108864);
  float* ctxln = (float*)(ws + (size_t)83886080);         // 16 MB, live to end
  char*  small = ws + (size_t)100663296;
  int*   idx0  = (int*)(small + 0);
  int*   idx1  = (int*)(small + 32768);
  float* w0a   = (float*)(small + 65536);
  float* w1a   = (float*)(small + 98304);
  int*   lrowp = (int*)(small + 131072);
  float* lwv   = (float*)(small + 198656);
  int*   cnts  = (int*)(small + 266240);

  dim3 blk(256);
  // QKV projections: bf16 out (q scaled by 1/8)
  mfma_gemm<<<dim3(4, 128, 1), blk, 0, stream>>>(x, DM, wq, nullptr, nullptr, nullptr, nullptr,
      nullptr, qbf, nullptr, NTOK, DM, DM, 0, 0.125f);
  mfma_gemm<<<dim3(4, 128, 1), blk, 0, stream>>>(x, DM, wk, nullptr, nullptr, nullptr, nullptr,
      nullptr, kbf, nullptr, NTOK, DM, DM, 0, 1.0f);
  mfma_gemm<<<dim3(4, 128, 1), blk, 0, stream>>>(x, DM, wv, nullptr, nullptr, nullptr, nullptr,
      nullptr, vbf, nullptr, NTOK, DM, DM, 0, 1.0f);
  // attention
  attn_mfma<<<dim3(16, 64), blk, 0, stream>>>(qbf, kbf, vbf, ctxb);
  // y0 = relu(ctx@wo) + x
  mfma_gemm<<<dim3(4, 128, 1), blk, 0, stream>>>(ctxb, DM, wo, nullptr, nullptr, nullptr, nullptr,
      y0, nullptr, x, NTOK, DM, DM, 1, 1.0f);
  // ctx_ln = LN(y0)
  ln_kernel<<<8192, blk, 0, stream>>>(y0, nullptr, ctxln, DM, 0,
      ln_attn_g, ln_attn_g, ln_attn_g, ln_attn_g, ln_attn_b, ln_attn_b, ln_attn_b, ln_attn_b);
  // gating
  gate1<<<2048, blk, 0, stream>>>(ctxln, wg1, idx0, idx1, w0a, w1a);
  gate2<<<96, 64, 0, stream>>>(idx0, idx1, w0a, w1a, lrowp, lwv, cnts);
  // zero accumulators
  hipMemsetAsync(hb, 0, (size_t)NTOK * DI * 4, stream);
  hipMemsetAsync(ymoe, 0, (size_t)NTOK * DM * 4, stream);
  // MoE layer 1: h += w * (ctxln@W1[e] + b1[e])
  mfma_gemm<<<dim3(16, 3, 96), blk, 0, stream>>>(ctxln, DM, w1, b1, lrowp, lwv, cnts,
      hb, nullptr, nullptr, 0, DI, DM, 2, 1.0f);
  // h = relu(LN_g(h)) in place
  ln_kernel<<<8192, blk, 0, stream>>>(hb, nullptr, hb, DI, 1,
      ln1g, ln2g, ln3g, ln4g, ln1b, ln2b, ln3b, ln4b);
  // MoE layer 2: ymoe += w * (h@W2[e] + b2[e])
  mfma_gemm<<<dim3(4, 3, 96), blk, 0, stream>>>(hb, DI, w2, b2, lrowp, lwv, cnts,
      ymoe, nullptr, nullptr, 0, DM, DI, 2, 1.0f);
  // out = LN(ymoe + ctxln)
  ln_kernel<<<8192, blk, 0, stream>>>(ymoe, ctxln, (float*)d_out, DM, 0,
      ln_out_g, ln_out_g, ln_out_g, ln_out_g, ln_out_b, ln_out_b, ln_out_b, ln_out_b);
}